// Round 9
// baseline (886.234 us; speedup 1.0000x reference)
//
#include <hip/hip_runtime.h>

// LightplaneSplatter: trilinear scatter-splat of per-ray encodings (C=16)
// into a (1,128,128,128,16) fp32 grid.
//
// Round 9: identical to round 8 EXCEPT the LDS tile accumulation uses
// unsafeAtomicAdd (native ds_add_f32, fire-and-forget) instead of safe
// atomicAdd (CAS retry loop). Theory: the CAS loop's dependent LDS
// round-trips + contention retries were the entire 670 us of accum_kernel
// (R7 vs R8 timing identical despite totally different fetch paths).

#define NS   64
#define NSI  8
#define ST   (NS + NSI)   // 72
#define GD   128
#define GH   128
#define GW   128
#define GC   16
#define DISP_INF 1e-4f

#define NTT   16                    // tiles per axis (8 points each)
#define NBINS (NTT * NTT * NTT)     // 4096
#define TILE_FL (8 * 8 * 8 * GC)    // 8192 floats = 32 KB
#define CHK   512                   // samples per chunk
#define MULTI_FLAG 0x80000000u

// ---------------------------------------------------------------------------
__device__ __forceinline__ bool compute_sample(
    const float* __restrict__ dirs, const float* __restrict__ orig,
    const float* __restrict__ nearv, const float* __restrict__ farv,
    int ray, int s,
    int& ix, int& iy, int& iz, float& fx, float& fy, float& fz)
{
    float nr = nearv[ray], fr = farv[ray];
    float t;
    if (s < NS) {
        float frac = ((float)s + 0.5f) * (1.0f / (float)NS);
        t = nr + (fr - nr) * frac;
    } else {
        float j    = (float)(s - NS + 1) * (1.0f / (float)NSI);
        float invf = 1.0f / fr;
        float disp = invf + (DISP_INF - invf) * j;
        t = 1.0f / disp;
    }
    float px = orig[ray*3+0] + t * dirs[ray*3+0];
    float py = orig[ray*3+1] + t * dirs[ray*3+1];
    float pz = orig[ray*3+2] + t * dirs[ray*3+2];
    float vx = (px + 1.0f) * 0.5f * 127.0f;
    float vy = (py + 1.0f) * 0.5f * 127.0f;
    float vz = (pz + 1.0f) * 0.5f * 127.0f;
    float bx = floorf(vx), by = floorf(vy), bz = floorf(vz);
    fx = vx - bx; fy = vy - by; fz = vz - bz;
    ix = (int)bx; iy = (int)by; iz = (int)bz;
    return !(ix < -1 || ix > GW - 1 ||
             iy < -1 || iy > GH - 1 ||
             iz < -1 || iz > GD - 1);
}

// Tile range touched by base cell i along one axis (i in [-1, 127]).
__device__ __forceinline__ void tile_range(int i, int& t0, int& t1)
{
    t0 = (i < 0 ? 0 : i) >> 3;
    t1 = (i + 1 > 127 ? 127 : i + 1) >> 3;
}

// ---------------------------------------------------------------------------
// Pass A: per-tile sample counts (with duplication for boundary footprints).
__global__ __launch_bounds__(256) void count_kernel(
    const float* __restrict__ dirs, const float* __restrict__ orig,
    const float* __restrict__ nearv, const float* __restrict__ farv,
    int* __restrict__ counts, int total)
{
    __shared__ int h[NBINS];
    for (int i = threadIdx.x; i < NBINS; i += 256) h[i] = 0;
    __syncthreads();
    for (int idx = blockIdx.x * 256 + threadIdx.x; idx < total;
         idx += gridDim.x * 256) {
        int ray = idx / ST, s = idx - (idx / ST) * ST;
        int ix, iy, iz; float fx, fy, fz;
        if (!compute_sample(dirs, orig, nearv, farv, ray, s, ix, iy, iz, fx, fy, fz))
            continue;
        int tx0, tx1, ty0, ty1, tz0, tz1;
        tile_range(ix, tx0, tx1); tile_range(iy, ty0, ty1); tile_range(iz, tz0, tz1);
        for (int tz = tz0; tz <= tz1; ++tz)
            for (int ty = ty0; ty <= ty1; ++ty)
                for (int tx = tx0; tx <= tx1; ++tx)
                    atomicAdd(&h[(tz * NTT + ty) * NTT + tx], 1);
    }
    __syncthreads();
    for (int i = threadIdx.x; i < NBINS; i += 256)
        if (h[i]) atomicAdd(&counts[i], h[i]);
}

// ---------------------------------------------------------------------------
// Pass B: scan counts -> offsets/cursor; emit chunk table.
__global__ __launch_bounds__(256) void scan_kernel(
    const int* __restrict__ counts, int* __restrict__ offsets,
    int* __restrict__ cursor, unsigned int* __restrict__ chunk_info,
    int* __restrict__ nck)
{
    __shared__ int p1[256], p2[256];
    const int CH = NBINS / 256;  // 16
    int tid = threadIdx.x;
    int base = tid * CH;
    int s1 = 0, s2 = 0;
    for (int i = 0; i < CH; ++i) {
        int c = counts[base + i];
        s1 += c;
        s2 += (c + CHK - 1) / CHK;
    }
    p1[tid] = s1; p2[tid] = s2;
    __syncthreads();
    if (tid == 0) {
        int a1 = 0, a2 = 0;
        for (int i = 0; i < 256; ++i) {
            int v1 = p1[i], v2 = p2[i];
            p1[i] = a1; p2[i] = a2;
            a1 += v1; a2 += v2;
        }
        nck[0] = a2;
    }
    __syncthreads();
    int run = p1[tid];
    int crun = p2[tid];
    for (int i = 0; i < CH; ++i) {
        int bin = base + i;
        int c = counts[bin];
        offsets[bin] = run;
        cursor[bin]  = run;
        int nc = (c + CHK - 1) / CHK;
        unsigned int mf = (nc > 1) ? MULTI_FLAG : 0u;
        for (int k = 0; k < nc; ++k)
            chunk_info[crun + k] = (unsigned int)bin | ((unsigned int)k << 12) | mf;
        crun += nc;
        run += c;
    }
}

// ---------------------------------------------------------------------------
// Pass C: scatter fat records into per-tile lists.
// Record: float4 { uint pack = ray<<12 | (lz0+1)<<8 | (ly0+1)<<4 | (lx0+1),
//                  fx, fy, fz }  with l*0 = base cell relative to tile origin.
__global__ __launch_bounds__(256) void scatter_kernel(
    const float* __restrict__ dirs, const float* __restrict__ orig,
    const float* __restrict__ nearv, const float* __restrict__ farv,
    int* __restrict__ cursor, float4* __restrict__ recs, int total, int cap)
{
    int idx = blockIdx.x * 256 + threadIdx.x;
    if (idx >= total) return;
    int ray = idx / ST, s = idx - (idx / ST) * ST;
    int ix, iy, iz; float fx, fy, fz;
    if (!compute_sample(dirs, orig, nearv, farv, ray, s, ix, iy, iz, fx, fy, fz))
        return;
    int tx0, tx1, ty0, ty1, tz0, tz1;
    tile_range(ix, tx0, tx1); tile_range(iy, ty0, ty1); tile_range(iz, tz0, tz1);
    for (int tz = tz0; tz <= tz1; ++tz)
        for (int ty = ty0; ty <= ty1; ++ty)
            for (int tx = tx0; tx <= tx1; ++tx) {
                int bin = (tz * NTT + ty) * NTT + tx;
                int slot = atomicAdd(&cursor[bin], 1);
                if (slot < cap) {
                    unsigned int pk = ((unsigned int)ray << 12)
                                    | ((unsigned int)(iz - (tz << 3) + 1) << 8)
                                    | ((unsigned int)(iy - (ty << 3) + 1) << 4)
                                    |  (unsigned int)(ix - (tx << 3) + 1);
                    recs[slot] = make_float4(__uint_as_float(pk), fx, fy, fz);
                }
            }
}

// ---------------------------------------------------------------------------
// Pass D: one block per chunk; 2-deep pipelined accumulate into LDS; flush.
__global__ __launch_bounds__(256) void accum_kernel(
    const float* __restrict__ enc,
    const int* __restrict__ offsets, const int* __restrict__ counts,
    const float4* __restrict__ recs, const unsigned int* __restrict__ chunk_info,
    const int* __restrict__ nck,
    float* __restrict__ grid)
{
    if ((int)blockIdx.x >= nck[0]) return;
    unsigned int info = chunk_info[blockIdx.x];
    int bin  = (int)(info & 0xFFFu);
    int k    = (int)((info >> 12) & 0x7FFFFu);
    bool multi = (info & MULTI_FLAG) != 0;
    int cnt  = counts[bin];
    int start = offsets[bin] + k * CHK;
    int n = cnt - k * CHK; if (n > CHK) n = CHK;

    int tx = bin & 15, ty = (bin >> 4) & 15, tz = bin >> 8;
    int gx0 = tx << 3, gy0 = ty << 3, gz0 = tz << 3;

    __shared__ float tile[TILE_FL];
    {
        float4* t4 = (float4*)tile;
        for (int i = threadIdx.x; i < TILE_FL / 4; i += 256)
            t4[i] = make_float4(0.f, 0.f, 0.f, 0.f);
    }
    __syncthreads();

    int group = threadIdx.x >> 4;
    int c     = threadIdx.x & 15;

    // 2-deep software pipeline over records [start, start+n), stride 16.
    float4 R0 = make_float4(0.f, 0.f, 0.f, 0.f);
    float4 R1 = R0;
    float  ev0 = 0.f;
    if (group < n) {
        R0 = recs[start + group];
        ev0 = enc[(__float_as_uint(R0.x) >> 12) * GC + c];
    }
    if (group + 16 < n) R1 = recs[start + group + 16];

    for (int r = group; r < n; r += 16) {
        float4 R2 = R1;
        float ev1 = ev0;
        if (r + 32 < n) R2 = recs[start + r + 32];
        if (r + 16 < n) ev1 = enc[(__float_as_uint(R1.x) >> 12) * GC + c];

        unsigned int pk = __float_as_uint(R0.x);
        int lx0 = (int)(pk & 15u) - 1;
        int ly0 = (int)((pk >> 4) & 15u) - 1;
        int lz0 = (int)((pk >> 8) & 15u) - 1;
        float fx = R0.y, fy = R0.z, fz = R0.w;
        float gx_ = 1.0f - fx, gy_ = 1.0f - fy, gz_ = 1.0f - fz;
        #pragma unroll
        for (int corner = 0; corner < 8; ++corner) {
            int cx = corner & 1, cy = (corner >> 1) & 1, cz = (corner >> 2) & 1;
            int lx = lx0 + cx, ly = ly0 + cy, lz = lz0 + cz;
            if ((unsigned)lx < 8u && (unsigned)ly < 8u && (unsigned)lz < 8u) {
                float w = (cx ? fx : gx_) * (cy ? fy : gy_) * (cz ? fz : gz_);
                // NATIVE LDS fp32 atomic (ds_add_f32), not a CAS loop.
                unsafeAtomicAdd(&tile[(((lz << 3) + ly) << 3 | lx) * GC + c], w * ev0);
            }
        }
        R0 = R1; ev0 = ev1; R1 = R2;
    }
    __syncthreads();

    if (!multi) {
        // Exclusive tile: plain float4 stores, skipping all-zero quads
        // (grid is pre-zeroed by memset).
        const float4* t4 = (const float4*)tile;
        float4* o4 = (float4*)grid;
        for (int i = threadIdx.x; i < TILE_FL / 4; i += 256) {
            float4 v = t4[i];
            if (v.x == 0.f && v.y == 0.f && v.z == 0.f && v.w == 0.f) continue;
            int row = i >> 5;                 // 64 rows of 128 floats (z,y fixed)
            int col = i & 31;                 // float4 within row
            int lz = row >> 3, ly = row & 7;
            size_t gf = ((((size_t)((gz0 + lz) * GH + gy0 + ly)) * GW + gx0) * GC) >> 2;
            o4[gf + col] = v;
        }
    } else {
        // Shared tile: atomic adds, skip all-zero points.
        for (int p = group; p < 512; p += 16) {
            float v = tile[p * GC + c];
            unsigned long long m = __ballot(v != 0.0f);
            if (((m >> (threadIdx.x & 48)) & 0xFFFFull) == 0ull) continue;
            int gx = gx0 + (p & 7), gy = gy0 + ((p >> 3) & 7), gz = gz0 + (p >> 6);
            unsafeAtomicAdd(&grid[((gz * GH + gy) * GW + gx) * GC + c], v);
        }
    }
}

// ---------------------------------------------------------------------------
// Fallback: direct atomic splat (round-1 kernel) if d_ws is too small.
__global__ __launch_bounds__(256) void splat_direct(
    const float* __restrict__ dirs, const float* __restrict__ orig,
    const float* __restrict__ nearv, const float* __restrict__ farv,
    const float* __restrict__ enc,
    float* __restrict__ grid, int n_rays)
{
    int gt = blockIdx.x * blockDim.x + threadIdx.x;
    int group = gt >> 4;
    int c = gt & 15;
    if (group >= n_rays * ST) return;
    int ray = group / ST;
    int s   = group - ray * ST;
    int ix, iy, iz; float fx, fy, fz;
    if (!compute_sample(dirs, orig, nearv, farv, ray, s, ix, iy, iz, fx, fy, fz))
        return;
    float ev = enc[ray * GC + c];
    float gx0 = 1.0f - fx, gy0 = 1.0f - fy, gz0 = 1.0f - fz;
    #pragma unroll
    for (int corner = 0; corner < 8; ++corner) {
        int cx = corner & 1, cy = (corner >> 1) & 1, cz = (corner >> 2) & 1;
        int jx = ix + cx, jy = iy + cy, jz = iz + cz;
        if (jx < 0 || jx >= GW || jy < 0 || jy >= GH || jz < 0 || jz >= GD) continue;
        float w = (cx ? fx : gx0) * (cy ? fy : gy0) * (cz ? fz : gz0);
        unsafeAtomicAdd(&grid[((jz * GH + jy) * GW + jx) * GC + c], w * ev);
    }
}

// ---------------------------------------------------------------------------
extern "C" void kernel_launch(void* const* d_in, const int* in_sizes, int n_in,
                              void* d_out, int out_size, void* d_ws, size_t ws_size,
                              hipStream_t stream) {
    const float* dirs  = (const float*)d_in[0];
    const float* orig  = (const float*)d_in[1];
    const float* nearv = (const float*)d_in[2];
    const float* farv  = (const float*)d_in[3];
    const float* enc   = (const float*)d_in[4];
    float* out = (float*)d_out;

    int n_rays = in_sizes[2];
    int total  = n_rays * ST;

    hipMemsetAsync(out, 0, (size_t)out_size * sizeof(float), stream);

    // Workspace layout: [counts|offsets|cursor|nck|chunk_info| (align16) recs]
    int cap = total + total / 2;                 // record capacity (~1.5x)
    int maxck = NBINS + cap / CHK + 2;           // chunk-table bound
    size_t prefix_ints = (size_t)NBINS * 3 + 1 + (size_t)maxck;
    prefix_ints = (prefix_ints + 3) & ~(size_t)3;        // align recs to 16 B
    size_t need = prefix_ints * 4 + (size_t)cap * 16;

    if (ws_size < need || n_rays >= (1 << 20)) {
        long long tthreads = (long long)total * 16;
        int blocks = (int)((tthreads + 255) / 256);
        splat_direct<<<blocks, 256, 0, stream>>>(dirs, orig, nearv, farv, enc,
                                                 out, n_rays);
        return;
    }

    int* counts  = (int*)d_ws;
    int* offsets = counts + NBINS;
    int* cursor  = offsets + NBINS;
    int* nck     = cursor + NBINS;
    unsigned int* chunk_info = (unsigned int*)(nck + 1);
    float4* recs = (float4*)((int*)d_ws + prefix_ints);

    hipMemsetAsync(counts, 0, NBINS * sizeof(int), stream);
    count_kernel<<<1024, 256, 0, stream>>>(dirs, orig, nearv, farv, counts, total);
    scan_kernel<<<1, 256, 0, stream>>>(counts, offsets, cursor, chunk_info, nck);
    scatter_kernel<<<(total + 255) / 256, 256, 0, stream>>>(
        dirs, orig, nearv, farv, cursor, recs, total, cap);
    accum_kernel<<<maxck, 256, 0, stream>>>(
        enc, offsets, counts, recs, chunk_info, nck, out);
}

// Round 10
// 579.318 us; speedup vs baseline: 1.5298x; 1.5298x over previous
//
#include <hip/hip_runtime.h>

// LightplaneSplatter: trilinear scatter-splat of per-ray encodings (C=16)
// into a (1,128,128,128,16) fp32 grid.
//
// Round 10: accum WITHOUT LDS atomics.
//   R7/R8/R9 (three different fetch structures) all timed identically at
//   ~670us with the machine 94% idle -> the invariant LDS fp32 atomic-RMW
//   corner loop is the bottleneck (LDS atomic adds are far slower than
//   plain ds ops). New accum: one record per wave, 64 lanes = 8 corners x
//   8 channels (all-distinct addresses), 2 channel-split waves per block
//   (disjoint address sets) -> plain ds_read/v_add/ds_write, zero atomics.
//   Bank-swizzle (c + 8lx + 4ly)&15 makes corner lanes 2-way-conflict max.

#define NS   64
#define NSI  8
#define ST   (NS + NSI)   // 72
#define GD   128
#define GH   128
#define GW   128
#define GC   16
#define DISP_INF 1e-4f

#define NTT   16                    // tiles per axis (8 points each)
#define NBINS (NTT * NTT * NTT)     // 4096
#define TILE_FL (8 * 8 * 8 * GC)    // 8192 floats = 32 KB
#define CHK   512                   // samples per chunk
#define MULTI_FLAG 0x80000000u
#define ACC_THREADS 128             // 2 waves (channel-split)

// ---------------------------------------------------------------------------
__device__ __forceinline__ bool compute_sample(
    const float* __restrict__ dirs, const float* __restrict__ orig,
    const float* __restrict__ nearv, const float* __restrict__ farv,
    int ray, int s,
    int& ix, int& iy, int& iz, float& fx, float& fy, float& fz)
{
    float nr = nearv[ray], fr = farv[ray];
    float t;
    if (s < NS) {
        float frac = ((float)s + 0.5f) * (1.0f / (float)NS);
        t = nr + (fr - nr) * frac;
    } else {
        float j    = (float)(s - NS + 1) * (1.0f / (float)NSI);
        float invf = 1.0f / fr;
        float disp = invf + (DISP_INF - invf) * j;
        t = 1.0f / disp;
    }
    float px = orig[ray*3+0] + t * dirs[ray*3+0];
    float py = orig[ray*3+1] + t * dirs[ray*3+1];
    float pz = orig[ray*3+2] + t * dirs[ray*3+2];
    float vx = (px + 1.0f) * 0.5f * 127.0f;
    float vy = (py + 1.0f) * 0.5f * 127.0f;
    float vz = (pz + 1.0f) * 0.5f * 127.0f;
    float bx = floorf(vx), by = floorf(vy), bz = floorf(vz);
    fx = vx - bx; fy = vy - by; fz = vz - bz;
    ix = (int)bx; iy = (int)by; iz = (int)bz;
    return !(ix < -1 || ix > GW - 1 ||
             iy < -1 || iy > GH - 1 ||
             iz < -1 || iz > GD - 1);
}

// Tile range touched by base cell i along one axis (i in [-1, 127]).
__device__ __forceinline__ void tile_range(int i, int& t0, int& t1)
{
    t0 = (i < 0 ? 0 : i) >> 3;
    t1 = (i + 1 > 127 ? 127 : i + 1) >> 3;
}

// ---------------------------------------------------------------------------
// Pass A: per-tile sample counts (with duplication for boundary footprints).
__global__ __launch_bounds__(256) void count_kernel(
    const float* __restrict__ dirs, const float* __restrict__ orig,
    const float* __restrict__ nearv, const float* __restrict__ farv,
    int* __restrict__ counts, int total)
{
    __shared__ int h[NBINS];
    for (int i = threadIdx.x; i < NBINS; i += 256) h[i] = 0;
    __syncthreads();
    for (int idx = blockIdx.x * 256 + threadIdx.x; idx < total;
         idx += gridDim.x * 256) {
        int ray = idx / ST, s = idx - (idx / ST) * ST;
        int ix, iy, iz; float fx, fy, fz;
        if (!compute_sample(dirs, orig, nearv, farv, ray, s, ix, iy, iz, fx, fy, fz))
            continue;
        int tx0, tx1, ty0, ty1, tz0, tz1;
        tile_range(ix, tx0, tx1); tile_range(iy, ty0, ty1); tile_range(iz, tz0, tz1);
        for (int tz = tz0; tz <= tz1; ++tz)
            for (int ty = ty0; ty <= ty1; ++ty)
                for (int tx = tx0; tx <= tx1; ++tx)
                    atomicAdd(&h[(tz * NTT + ty) * NTT + tx], 1);
    }
    __syncthreads();
    for (int i = threadIdx.x; i < NBINS; i += 256)
        if (h[i]) atomicAdd(&counts[i], h[i]);
}

// ---------------------------------------------------------------------------
// Pass B: scan counts -> offsets/cursor; emit chunk table.
__global__ __launch_bounds__(256) void scan_kernel(
    const int* __restrict__ counts, int* __restrict__ offsets,
    int* __restrict__ cursor, unsigned int* __restrict__ chunk_info,
    int* __restrict__ nck)
{
    __shared__ int p1[256], p2[256];
    const int CH = NBINS / 256;  // 16
    int tid = threadIdx.x;
    int base = tid * CH;
    int s1 = 0, s2 = 0;
    for (int i = 0; i < CH; ++i) {
        int c = counts[base + i];
        s1 += c;
        s2 += (c + CHK - 1) / CHK;
    }
    p1[tid] = s1; p2[tid] = s2;
    __syncthreads();
    if (tid == 0) {
        int a1 = 0, a2 = 0;
        for (int i = 0; i < 256; ++i) {
            int v1 = p1[i], v2 = p2[i];
            p1[i] = a1; p2[i] = a2;
            a1 += v1; a2 += v2;
        }
        nck[0] = a2;
    }
    __syncthreads();
    int run = p1[tid];
    int crun = p2[tid];
    for (int i = 0; i < CH; ++i) {
        int bin = base + i;
        int c = counts[bin];
        offsets[bin] = run;
        cursor[bin]  = run;
        int nc = (c + CHK - 1) / CHK;
        unsigned int mf = (nc > 1) ? MULTI_FLAG : 0u;
        for (int k = 0; k < nc; ++k)
            chunk_info[crun + k] = (unsigned int)bin | ((unsigned int)k << 12) | mf;
        crun += nc;
        run += c;
    }
}

// ---------------------------------------------------------------------------
// Pass C: scatter fat records into per-tile lists.
// Record: float4 { uint pack = ray<<12 | (lz0+1)<<8 | (ly0+1)<<4 | (lx0+1),
//                  fx, fy, fz }  with l*0 = base cell relative to tile origin.
__global__ __launch_bounds__(256) void scatter_kernel(
    const float* __restrict__ dirs, const float* __restrict__ orig,
    const float* __restrict__ nearv, const float* __restrict__ farv,
    int* __restrict__ cursor, float4* __restrict__ recs, int total, int cap)
{
    int idx = blockIdx.x * 256 + threadIdx.x;
    if (idx >= total) return;
    int ray = idx / ST, s = idx - (idx / ST) * ST;
    int ix, iy, iz; float fx, fy, fz;
    if (!compute_sample(dirs, orig, nearv, farv, ray, s, ix, iy, iz, fx, fy, fz))
        return;
    int tx0, tx1, ty0, ty1, tz0, tz1;
    tile_range(ix, tx0, tx1); tile_range(iy, ty0, ty1); tile_range(iz, tz0, tz1);
    for (int tz = tz0; tz <= tz1; ++tz)
        for (int ty = ty0; ty <= ty1; ++ty)
            for (int tx = tx0; tx <= tx1; ++tx) {
                int bin = (tz * NTT + ty) * NTT + tx;
                int slot = atomicAdd(&cursor[bin], 1);
                if (slot < cap) {
                    unsigned int pk = ((unsigned int)ray << 12)
                                    | ((unsigned int)(iz - (tz << 3) + 1) << 8)
                                    | ((unsigned int)(iy - (ty << 3) + 1) << 4)
                                    |  (unsigned int)(ix - (tx << 3) + 1);
                    recs[slot] = make_float4(__uint_as_float(pk), fx, fy, fz);
                }
            }
}

// ---------------------------------------------------------------------------
// Pass D: one block (2 waves) per chunk. One record per wave per iteration:
// lane = corner(8) x channel8(8); wave w owns channels [8w, 8w+8).
// Plain LDS read-modify-write, no atomics (all lane addresses distinct,
// wave address sets disjoint, records serial within wave).
__global__ __launch_bounds__(ACC_THREADS) void accum_kernel(
    const float* __restrict__ enc,
    const int* __restrict__ offsets, const int* __restrict__ counts,
    const float4* __restrict__ recs, const unsigned int* __restrict__ chunk_info,
    const int* __restrict__ nck,
    float* __restrict__ grid)
{
    if ((int)blockIdx.x >= nck[0]) return;
    unsigned int info = chunk_info[blockIdx.x];
    int bin  = (int)(info & 0xFFFu);
    int k    = (int)((info >> 12) & 0x7FFFFu);
    bool multi = (info & MULTI_FLAG) != 0;
    int cnt  = counts[bin];
    int start = offsets[bin] + k * CHK;
    int n = cnt - k * CHK; if (n > CHK) n = CHK;

    int tx = bin & 15, ty = (bin >> 4) & 15, tz = bin >> 8;
    int gx0 = tx << 3, gy0 = ty << 3, gz0 = tz << 3;

    __shared__ float tile[TILE_FL];
    {
        float4* t4 = (float4*)tile;
        for (int i = threadIdx.x; i < TILE_FL / 4; i += ACC_THREADS)
            t4[i] = make_float4(0.f, 0.f, 0.f, 0.f);
    }
    __syncthreads();

    int lane   = threadIdx.x & 63;
    int wave   = threadIdx.x >> 6;      // 0 or 1
    int corner = lane >> 3;             // 0..7
    int c      = wave * 8 + (lane & 7); // owned channel
    int cx = corner & 1, cy = (corner >> 1) & 1, cz = (corner >> 2) & 1;

    // 2-deep pipeline over records; both waves walk the full list.
    float4 R0 = make_float4(0.f,0.f,0.f,0.f), R1 = R0;
    float ev0 = 0.f;
    if (n > 0) {
        R0 = recs[start];
        ev0 = enc[(__float_as_uint(R0.x) >> 12) * GC + c];
        if (n > 1) R1 = recs[start + 1];
    }

    for (int r = 0; r < n; ++r) {
        float4 R2 = R1;
        float ev1 = ev0;
        if (r + 2 < n) R2 = recs[start + r + 2];
        if (r + 1 < n) ev1 = enc[(__float_as_uint(R1.x) >> 12) * GC + c];

        unsigned int pk = __float_as_uint(R0.x);
        int lx = (int)(pk & 15u)        - 1 + cx;
        int ly = (int)((pk >> 4) & 15u) - 1 + cy;
        int lz = (int)((pk >> 8) & 15u) - 1 + cz;
        float fx = R0.y, fy = R0.z, fz = R0.w;
        if ((unsigned)lx < 8u && (unsigned)ly < 8u && (unsigned)lz < 8u) {
            float wx = cx ? fx : 1.0f - fx;
            float wy = cy ? fy : 1.0f - fy;
            float wz = cz ? fz : 1.0f - fz;
            int point = ((lz << 3) + ly) * 8 + lx;
            int m = (c + 8 * lx + 4 * ly) & 15;      // bank swizzle
            tile[point * GC + m] += wx * wy * wz * ev0;   // plain ds RMW
        }
        R0 = R1; ev0 = ev1; R1 = R2;
    }
    __syncthreads();

    if (!multi) {
        // Exclusive tile: gather 4 swizzled scalars -> zero-skipped float4 store.
        for (int i = threadIdx.x; i < TILE_FL / 4; i += ACC_THREADS) {
            int point = i >> 2;
            int q = (i & 3) * 4;                     // starting channel of quad
            int lx = point & 7, ly = (point >> 3) & 7, lz = point >> 6;
            int s = 8 * lx + 4 * ly;
            float v0 = tile[point * GC + ((q + 0 + s) & 15)];
            float v1 = tile[point * GC + ((q + 1 + s) & 15)];
            float v2 = tile[point * GC + ((q + 2 + s) & 15)];
            float v3 = tile[point * GC + ((q + 3 + s) & 15)];
            if (v0 == 0.f && v1 == 0.f && v2 == 0.f && v3 == 0.f) continue;
            size_t gf = (((size_t)((gz0 + lz) * GH + gy0 + ly)) * GW + gx0 + lx) * GC + q;
            *(float4*)&grid[gf] = make_float4(v0, v1, v2, v3);
        }
    } else {
        // Shared tile: zero-skipped global atomics.
        int group = threadIdx.x >> 4;   // 0..7
        int cc    = threadIdx.x & 15;
        for (int p = group; p < 512; p += 8) {
            int lx = p & 7, ly = (p >> 3) & 7, lz = p >> 6;
            float v = tile[p * GC + ((cc + 8 * lx + 4 * ly) & 15)];
            unsigned long long mbal = __ballot(v != 0.0f);
            if (((mbal >> (threadIdx.x & 48)) & 0xFFFFull) == 0ull) continue;
            unsafeAtomicAdd(&grid[(((gz0 + lz) * GH + gy0 + ly) * GW + gx0 + lx) * GC + cc], v);
        }
    }
}

// ---------------------------------------------------------------------------
// Fallback: direct atomic splat (round-1 kernel) if d_ws is too small.
__global__ __launch_bounds__(256) void splat_direct(
    const float* __restrict__ dirs, const float* __restrict__ orig,
    const float* __restrict__ nearv, const float* __restrict__ farv,
    const float* __restrict__ enc,
    float* __restrict__ grid, int n_rays)
{
    int gt = blockIdx.x * blockDim.x + threadIdx.x;
    int group = gt >> 4;
    int c = gt & 15;
    if (group >= n_rays * ST) return;
    int ray = group / ST;
    int s   = group - ray * ST;
    int ix, iy, iz; float fx, fy, fz;
    if (!compute_sample(dirs, orig, nearv, farv, ray, s, ix, iy, iz, fx, fy, fz))
        return;
    float ev = enc[ray * GC + c];
    float gx0 = 1.0f - fx, gy0 = 1.0f - fy, gz0 = 1.0f - fz;
    #pragma unroll
    for (int corner = 0; corner < 8; ++corner) {
        int cx = corner & 1, cy = (corner >> 1) & 1, cz = (corner >> 2) & 1;
        int jx = ix + cx, jy = iy + cy, jz = iz + cz;
        if (jx < 0 || jx >= GW || jy < 0 || jy >= GH || jz < 0 || jz >= GD) continue;
        float w = (cx ? fx : gx0) * (cy ? fy : gy0) * (cz ? fz : gz0);
        unsafeAtomicAdd(&grid[((jz * GH + jy) * GW + jx) * GC + c], w * ev);
    }
}

// ---------------------------------------------------------------------------
extern "C" void kernel_launch(void* const* d_in, const int* in_sizes, int n_in,
                              void* d_out, int out_size, void* d_ws, size_t ws_size,
                              hipStream_t stream) {
    const float* dirs  = (const float*)d_in[0];
    const float* orig  = (const float*)d_in[1];
    const float* nearv = (const float*)d_in[2];
    const float* farv  = (const float*)d_in[3];
    const float* enc   = (const float*)d_in[4];
    float* out = (float*)d_out;

    int n_rays = in_sizes[2];
    int total  = n_rays * ST;

    hipMemsetAsync(out, 0, (size_t)out_size * sizeof(float), stream);

    // Workspace layout: [counts|offsets|cursor|nck|chunk_info| (align16) recs]
    int cap = total + total / 2;                 // record capacity (~1.5x)
    int maxck = NBINS + cap / CHK + 2;           // chunk-table bound
    size_t prefix_ints = (size_t)NBINS * 3 + 1 + (size_t)maxck;
    prefix_ints = (prefix_ints + 3) & ~(size_t)3;        // align recs to 16 B
    size_t need = prefix_ints * 4 + (size_t)cap * 16;

    if (ws_size < need || n_rays >= (1 << 20)) {
        long long tthreads = (long long)total * 16;
        int blocks = (int)((tthreads + 255) / 256);
        splat_direct<<<blocks, 256, 0, stream>>>(dirs, orig, nearv, farv, enc,
                                                 out, n_rays);
        return;
    }

    int* counts  = (int*)d_ws;
    int* offsets = counts + NBINS;
    int* cursor  = offsets + NBINS;
    int* nck     = cursor + NBINS;
    unsigned int* chunk_info = (unsigned int*)(nck + 1);
    float4* recs = (float4*)((int*)d_ws + prefix_ints);

    hipMemsetAsync(counts, 0, NBINS * sizeof(int), stream);
    count_kernel<<<1024, 256, 0, stream>>>(dirs, orig, nearv, farv, counts, total);
    scan_kernel<<<1, 256, 0, stream>>>(counts, offsets, cursor, chunk_info, nck);
    scatter_kernel<<<(total + 255) / 256, 256, 0, stream>>>(
        dirs, orig, nearv, farv, cursor, recs, total, cap);
    accum_kernel<<<maxck, ACC_THREADS, 0, stream>>>(
        enc, offsets, counts, recs, chunk_info, nck, out);
}